// Round 4
// baseline (14.131 us; speedup 1.0000x reference)
//
#include <hip/hip_runtime.h>

// SAConv: reference's scale = sqrt(heads // COUT) = 0 (Python int division)
// => softmax uniform => out = 7x7 box-mean of v = hswish(grouped_1x1(pad(x), wv)).
// q/k/rel_* are dead code.
//
// R3 (on top of the passing R2):
//  - weights hoisted LDS -> w[64] VGPRs once after the barrier (static indices),
//    removing the per-position 64x ds_read_b32 broadcast in the conv loop.
//  - P1 computes 2 x-positions per item with one aligned float2 load per
//    channel: pairs px = {2q+1, 2q+2} so xx0 = 2q-2 is even (8B aligned).
//    Positions with xx outside [0,56) are exactly zero => edge items write
//    zeros, no masked loads needed.
//  - P2/P3 identical to R2 (fully passed validation).

namespace {
constexpr int Bn = 8, CINn = 64, Hn = 56, Wn = 56;
constexpr int HEADSn = 8;
constexpr int PADn = 3;
constexpr int TH = 4;                  // output rows per block
constexpr int NTILES = Hn / TH;        // 14
constexpr int PH = TH + 6;             // 10 staged conv rows
constexpr int PW = Wn + 6;             // 62 staged cols
constexpr int RS = 80;                 // row stride in float4 (sx(61)=76 < 80)
constexpr int THREADS = 256;
constexpr int NRUNS = Wn / 2;          // 28 horizontal runs of 2
constexpr int QITEMS = 32;             // per row: q0..29 pairs, q30=px0, q31=px61
}

__device__ __forceinline__ int sx(int x) { return x + (x >> 2); }
__device__ __forceinline__ float4 f4add(float4 a, float4 b) {
    return make_float4(a.x + b.x, a.y + b.y, a.z + b.z, a.w + b.w);
}
__device__ __forceinline__ float4 f4sub(float4 a, float4 b) {
    return make_float4(a.x - b.x, a.y - b.y, a.z - b.z, a.w - b.w);
}

__global__ __launch_bounds__(THREADS) void saconv_r3(
    const float* __restrict__ x, const float* __restrict__ wv,
    float* __restrict__ out)
{
    __shared__ float  wvs[64];                 // this head's wv[o][i]
    __shared__ float4 vt[2 * PH * RS];         // 25.6 KB, [g4][py][sx(px)]
    __shared__ float4 vs[2 * TH * RS];         // 10.2 KB, [g4][y][sx(x)]

    const int bid  = blockIdx.x;
    const int tile = bid % NTILES;
    const int g    = (bid / NTILES) % HEADSn;
    const int b    = bid / (NTILES * HEADSn);
    const int h0   = tile * TH;
    const int tid  = threadIdx.x;

    if (tid < 64) wvs[tid] = wv[g * 64 + tid];
    __syncthreads();

    // hoist weights to registers (static indices -> VGPRs, one-time reads)
    float w[64];
    #pragma unroll
    for (int i = 0; i < 64; ++i) w[i] = wvs[i];

    const float* __restrict__ xg = x + (size_t)(b * CINn + g * 8) * (Hn * Wn);

    // ---- P1: conv(8->8) + hswish over padded tile, 2 positions/item ----
    for (int p = tid; p < PH * QITEMS; p += THREADS) {
        const int py = p / QITEMS;
        const int q  = p - py * QITEMS;
        const int y  = h0 + py - PADn;
        const bool yok = (unsigned)y < (unsigned)Hn;

        if (q < 30) {
            const int px0 = 2 * q + 1;          // positions px0, px0+1
            const int xx0 = px0 - PADn;         // even: 8B-aligned float2
            float4 v00 = make_float4(0.f,0.f,0.f,0.f), v01 = v00, v10 = v00, v11 = v00;
            if (yok && q >= 1 && q <= 28) {     // xx0 in [0,54]: both valid
                float in0[8], in1[8];
                #pragma unroll
                for (int i = 0; i < 8; ++i) {
                    const float2 t = *(const float2*)(xg + i * (Hn * Wn) + y * Wn + xx0);
                    in0[i] = t.x; in1[i] = t.y;
                }
                float a0[8], a1[8];
                #pragma unroll
                for (int o = 0; o < 8; ++o) {
                    float s0 = 0.f, s1 = 0.f;
                    #pragma unroll
                    for (int i = 0; i < 8; ++i) {
                        s0 = fmaf(w[o * 8 + i], in0[i], s0);
                        s1 = fmaf(w[o * 8 + i], in1[i], s1);
                    }
                    float t0 = fminf(fmaxf(s0 + 3.f, 0.f), 6.f);
                    float t1 = fminf(fmaxf(s1 + 3.f, 0.f), 6.f);
                    a0[o] = s0 * t0 * (1.f / 6.f);
                    a1[o] = s1 * t1 * (1.f / 6.f);
                }
                v00 = make_float4(a0[0], a0[1], a0[2], a0[3]);
                v01 = make_float4(a0[4], a0[5], a0[6], a0[7]);
                v10 = make_float4(a1[0], a1[1], a1[2], a1[3]);
                v11 = make_float4(a1[4], a1[5], a1[6], a1[7]);
            }
            vt[(0 * PH + py) * RS + sx(px0)]     = v00;
            vt[(1 * PH + py) * RS + sx(px0)]     = v01;
            vt[(0 * PH + py) * RS + sx(px0 + 1)] = v10;
            vt[(1 * PH + py) * RS + sx(px0 + 1)] = v11;
        } else {
            // q==30 -> px=0 (xx=-3), q==31 -> px=61 (xx=58): always zero
            const int px = (q == 30) ? 0 : (PW - 1);
            const float4 z = make_float4(0.f, 0.f, 0.f, 0.f);
            vt[(0 * PH + py) * RS + sx(px)] = z;
            vt[(1 * PH + py) * RS + sx(px)] = z;
        }
    }
    __syncthreads();

    // ---- P2: vertical 7-sum (sliding, 2 output rows per thread) ----
    if (tid < 2 * PW * 2) {
        const int g4 = tid & 1;
        const int r  = tid >> 1;
        const int xx = r % PW;
        const int yh = r / PW;
        const int y0 = 2 * yh;
        float4 rv[8];
        #pragma unroll
        for (int j = 0; j < 8; ++j)
            rv[j] = vt[(g4 * PH + y0 + j) * RS + sx(xx)];
        float4 s = rv[0];
        #pragma unroll
        for (int j = 1; j < 7; ++j) s = f4add(s, rv[j]);
        vs[(g4 * TH + y0) * RS + sx(xx)] = s;
        s = f4add(s, f4sub(rv[7], rv[0]));
        vs[(g4 * TH + y0 + 1) * RS + sx(xx)] = s;
    }
    __syncthreads();

    // ---- P3: horizontal 7-sum (sliding run of 2) + scale + store ----
    if (tid < TH * NRUNS * 2) {
        const int g4  = tid & 1;
        const int r   = tid >> 1;
        const int run = r % NRUNS;
        const int y   = r / NRUNS;
        const int x0  = run * 2;
        float4 rv[8];
        #pragma unroll
        for (int j = 0; j < 8; ++j)
            rv[j] = vs[(g4 * TH + y) * RS + sx(x0 + j)];
        float4 s0 = rv[0];
        #pragma unroll
        for (int j = 1; j < 7; ++j) s0 = f4add(s0, rv[j]);
        float4 s1 = f4add(s0, f4sub(rv[7], rv[0]));
        const float inv = 1.f / 49.f;
        float* ob = out + ((size_t)(b * CINn + g * 8 + g4 * 4) * Hn + (h0 + y)) * Wn + x0;
        const int plane = Hn * Wn;
        float2 st;
        st.x = s0.x * inv; st.y = s1.x * inv; *(float2*)(ob + 0 * plane) = st;
        st.x = s0.y * inv; st.y = s1.y * inv; *(float2*)(ob + 1 * plane) = st;
        st.x = s0.z * inv; st.y = s1.z * inv; *(float2*)(ob + 2 * plane) = st;
        st.x = s0.w * inv; st.y = s1.w * inv; *(float2*)(ob + 3 * plane) = st;
    }
}

extern "C" void kernel_launch(void* const* d_in, const int* in_sizes, int n_in,
                              void* d_out, int out_size, void* d_ws, size_t ws_size,
                              hipStream_t stream) {
    // setup_inputs order: x, wq, wk, wv, rel_h, rel_w
    const float* x  = (const float*)d_in[0];
    const float* wv = (const float*)d_in[3];
    float* out = (float*)d_out;

    dim3 grid(Bn * HEADSn * NTILES);   // 896 blocks
    saconv_r3<<<grid, THREADS, 0, stream>>>(x, wv, out);
}

// Round 5
// 13.304 us; speedup vs baseline: 1.0622x; 1.0622x over previous
//
#include <hip/hip_runtime.h>

// SAConv: reference's scale = sqrt(heads // COUT) = 0 (Python int division)
// => softmax uniform => out = 7x7 box-mean of v = hswish(grouped_1x1(pad(x), wv)).
// q/k/rel_* are dead code.
//
// R4: latency-oriented restructure. Grid 1792 blocks (b, head, 2-row tile)
// x 128 threads. Phase A: thread-per-(column, channel-half) computes the
// grouped 1x1 conv + hswish for 8 padded rows and the 2 vertical 7-sums in
// registers (2 running accumulators, weights in 32 VGPRs), writes 2 float4
// to a 5KB LDS buffer. ONE barrier. Phase B: horizontal sliding 7-sum
// (8 b128 reads -> 2 outputs) + float2 stores. LDS pipe ~free; occupancy
// ~14 waves/CU (vs R2's structure at ~3.5 blocks/CU with 36KB LDS).

namespace {
constexpr int Bn = 8, CINn = 64, Hn = 56, Wn = 56;
constexpr int HEADSn = 8;
constexpr int PADn = 3;
constexpr int TH = 2;                  // output rows per block
constexpr int NTILES = Hn / TH;        // 28
constexpr int PW = Wn + 6;             // 62 staged columns
constexpr int RSH = 78;                // hs row stride in float4 (sx(61)=76)
constexpr int THREADS = 128;
constexpr int NRUNS = Wn / 2;          // 28
}

__device__ __forceinline__ int sx(int x) { return x + (x >> 2); }
__device__ __forceinline__ float4 f4add(float4 a, float4 b) {
    return make_float4(a.x + b.x, a.y + b.y, a.z + b.z, a.w + b.w);
}
__device__ __forceinline__ float4 f4sub(float4 a, float4 b) {
    return make_float4(a.x - b.x, a.y - b.y, a.z - b.z, a.w - b.w);
}

__global__ __launch_bounds__(THREADS) void saconv_r4(
    const float* __restrict__ x, const float* __restrict__ wv,
    float* __restrict__ out)
{
    __shared__ float4 hs[2 * TH * RSH];   // [g4][y][sx(px)] = 4992 B

    const int bid  = blockIdx.x;
    const int tile = bid % NTILES;
    const int g    = (bid / NTILES) % HEADSn;
    const int b    = bid / (NTILES * HEADSn);
    const int h0   = tile * TH;
    const int tid  = threadIdx.x;

    // ---- Phase A: conv + hswish + vertical 7-sums, in registers ----
    const int g4 = tid >> 6;              // wave 0 -> out-ch 0..3, wave 1 -> 4..7
    const int px = tid & 63;              // staged column (0..61 valid)
    const int xx = px - PADn;
    const bool colok = (unsigned)xx < (unsigned)Wn;

    // this thread's 4 output channels' weights (32 VGPRs)
    const float* __restrict__ wg = wv + g * 64 + g4 * 32;
    float w[32];
    #pragma unroll
    for (int i = 0; i < 32; ++i) w[i] = wg[i];

    const float* __restrict__ xg = x + (size_t)(b * CINn + g * 8) * (Hn * Wn);

    float4 s0 = make_float4(0.f, 0.f, 0.f, 0.f);  // rows h0-3 .. h0+3
    float4 s1 = s0;                                // rows h0-2 .. h0+4
    #pragma unroll
    for (int r = 0; r < 8; ++r) {
        const int y = h0 + r - PADn;
        float4 v = make_float4(0.f, 0.f, 0.f, 0.f);
        if (colok && (unsigned)y < (unsigned)Hn) {
            float in[8];
            #pragma unroll
            for (int i = 0; i < 8; ++i)
                in[i] = xg[i * (Hn * Wn) + y * Wn + xx];
            float a[4];
            #pragma unroll
            for (int o = 0; o < 4; ++o) {
                float s = 0.f;
                #pragma unroll
                for (int i = 0; i < 8; ++i)
                    s = fmaf(w[o * 8 + i], in[i], s);
                float t = fminf(fmaxf(s + 3.f, 0.f), 6.f);
                a[o] = s * t * (1.f / 6.f);
            }
            v = make_float4(a[0], a[1], a[2], a[3]);
        }
        if (r < 7) s0 = f4add(s0, v);
        if (r >= 1) s1 = f4add(s1, v);
    }
    if (px < PW) {
        hs[(g4 * TH + 0) * RSH + sx(px)] = s0;
        hs[(g4 * TH + 1) * RSH + sx(px)] = s1;
    }
    __syncthreads();

    // ---- Phase B: horizontal sliding 7-sum + scale + store ----
    if (tid < TH * NRUNS * 2) {           // 112 threads
        const int g4b = tid & 1;
        const int rem = tid >> 1;
        const int run = rem % NRUNS;
        const int y   = rem / NRUNS;
        const int x0  = run * 2;
        float4 rv[8];
        #pragma unroll
        for (int j = 0; j < 8; ++j)
            rv[j] = hs[(g4b * TH + y) * RSH + sx(x0 + j)];
        float4 t0 = rv[0];
        #pragma unroll
        for (int j = 1; j < 7; ++j) t0 = f4add(t0, rv[j]);
        float4 t1 = f4add(t0, f4sub(rv[7], rv[0]));
        const float inv = 1.f / 49.f;
        float* ob = out + ((size_t)(b * CINn + g * 8 + g4b * 4) * Hn + (h0 + y)) * Wn + x0;
        const int plane = Hn * Wn;
        float2 st;
        st.x = t0.x * inv; st.y = t1.x * inv; *(float2*)(ob + 0 * plane) = st;
        st.x = t0.y * inv; st.y = t1.y * inv; *(float2*)(ob + 1 * plane) = st;
        st.x = t0.z * inv; st.y = t1.z * inv; *(float2*)(ob + 2 * plane) = st;
        st.x = t0.w * inv; st.y = t1.w * inv; *(float2*)(ob + 3 * plane) = st;
    }
}

extern "C" void kernel_launch(void* const* d_in, const int* in_sizes, int n_in,
                              void* d_out, int out_size, void* d_ws, size_t ws_size,
                              hipStream_t stream) {
    // setup_inputs order: x, wq, wk, wv, rel_h, rel_w
    const float* x  = (const float*)d_in[0];
    const float* wv = (const float*)d_in[3];
    float* out = (float*)d_out;

    dim3 grid(Bn * HEADSn * NTILES);   // 1792 blocks
    saconv_r4<<<grid, THREADS, 0, stream>>>(x, wv, out);
}

// Round 6
// 12.580 us; speedup vs baseline: 1.1233x; 1.0575x over previous
//
#include <hip/hip_runtime.h>

// SAConv: reference's scale = sqrt(heads // COUT) = 0 (Python int division)
// => softmax uniform => out = 7x7 box-mean of v = hswish(grouped_1x1(pad(x), wv)).
// q/k/rel_* are dead code.
//
// R5: conv-recompute-minimizing decomposition (R3/R4 showed the kernel is
// VALU-bound on conv positions: +334k positions cost +1.55us, matching the
// 2cyc/lane-op model). Tile = (b, head, 14-col output strip) spanning FULL
// height: grid 256 blocks == 1 block/CU, 1024 threads (16 waves/CU).
// Conv computed on 62 rows x 20 cols per block once: 317k total positions
// (1.29x global min) vs R2's 555k. Phases:
//   P1: conv+hswish -> vt[g4][row 62][col 20]  (thread owns one g4 half ->
//       w[32] regs only; consecutive lanes = consecutive cols)
//   P2: vertical sliding 7-sum down full columns (14 reads -> 8 outputs) -> vs
//   P3: horizontal sliding 7-sum (8 reads -> 2 outputs) + float2 stores
// LDS 79.5 KB (fine at 1 block/CU on gfx950).

namespace {
constexpr int Bn = 8, CINn = 64, Hn = 56, Wn = 56;
constexpr int HEADSn = 8;
constexpr int PADn = 3;
constexpr int XWO = 14;               // output cols per block
constexpr int NSTRIP = Wn / XWO;      // 4
constexpr int CC = XWO + 6;           // 20 conv cols
constexpr int CR = Hn + 6;            // 62 conv rows
constexpr int CSTR = 21;              // row stride in float4 (20 cols + 1 pad)
constexpr int THREADS = 1024;
constexpr int PLANE = Hn * Wn;        // 3136
}

__device__ __forceinline__ int vtIdx(int g4, int row, int col) {
    return (g4 * CR + row) * CSTR + col;
}
__device__ __forceinline__ int vsIdx(int g4, int row, int col) {
    return (g4 * Hn + row) * CSTR + col;
}
__device__ __forceinline__ float4 f4add(float4 a, float4 b) {
    return make_float4(a.x + b.x, a.y + b.y, a.z + b.z, a.w + b.w);
}
__device__ __forceinline__ float4 f4sub(float4 a, float4 b) {
    return make_float4(a.x - b.x, a.y - b.y, a.z - b.z, a.w - b.w);
}

__global__ __launch_bounds__(THREADS) void saconv_r5(
    const float* __restrict__ x, const float* __restrict__ wv,
    float* __restrict__ out)
{
    __shared__ float  wvs[64];
    __shared__ float4 vt[2 * CR * CSTR];   // 41.7 KB
    __shared__ float4 vs[2 * Hn * CSTR];   // 37.6 KB

    const int bid   = blockIdx.x;
    const int strip = bid & 3;
    const int g     = (bid >> 2) & 7;
    const int b     = bid >> 5;
    const int x0out = strip * XWO;
    const int tid   = threadIdx.x;

    if (tid < 64) wvs[tid] = wv[g * 64 + tid];
    __syncthreads();

    // ---- P1: conv(8->4 per thread-half) + hswish over 62x20 strip ----
    const int g4 = tid >> 9;          // threads 0..511: out-ch 0..3; 512..1023: 4..7
    const int t  = tid & 511;
    float w[32];
    #pragma unroll
    for (int i = 0; i < 32; ++i) w[i] = wvs[g4 * 32 + i];

    const float* __restrict__ xg = x + (size_t)(b * CINn + g * 8) * PLANE;

    for (int p = t; p < CR * CC; p += 512) {
        const int row = p / CC;
        const int col = p - row * CC;
        const int y   = row - PADn;
        const int xx  = x0out + col - PADn;
        float4 v = make_float4(0.f, 0.f, 0.f, 0.f);
        if ((unsigned)y < (unsigned)Hn && (unsigned)xx < (unsigned)Wn) {
            float in[8];
            #pragma unroll
            for (int i = 0; i < 8; ++i)
                in[i] = xg[i * PLANE + y * Wn + xx];
            float a[4];
            #pragma unroll
            for (int o = 0; o < 4; ++o) {
                float s = 0.f;
                #pragma unroll
                for (int i = 0; i < 8; ++i)
                    s = fmaf(w[o * 8 + i], in[i], s);
                float tt = fminf(fmaxf(s + 3.f, 0.f), 6.f);
                a[o] = s * tt * (1.f / 6.f);
            }
            v = make_float4(a[0], a[1], a[2], a[3]);
        }
        vt[vtIdx(g4, row, col)] = v;
    }
    __syncthreads();

    // ---- P2: vertical sliding 7-sum down full columns ----
    // item = (rowgrp 0..6, g4, col 0..19): 280 threads; 14 reads -> 8 outputs
    if (tid < 7 * 2 * CC) {
        const int col    = tid % CC;
        const int r      = tid / CC;
        const int g4b    = r & 1;
        const int rowgrp = r >> 1;
        const int r0     = rowgrp * 8;          // output rows r0..r0+7
        float4 win[14];
        #pragma unroll
        for (int j = 0; j < 14; ++j)
            win[j] = vt[vtIdx(g4b, r0 + j, col)];
        float4 s = win[0];
        #pragma unroll
        for (int j = 1; j < 7; ++j) s = f4add(s, win[j]);
        vs[vsIdx(g4b, r0, col)] = s;
        #pragma unroll
        for (int k = 1; k < 8; ++k) {
            s = f4add(s, f4sub(win[k + 6], win[k - 1]));
            vs[vsIdx(g4b, r0 + k, col)] = s;
        }
    }
    __syncthreads();

    // ---- P3: horizontal sliding 7-sum (run of 2) + scale + store ----
    // item = (y 0..55, g4, run 0..6): 784 threads, single pass
    if (tid < Hn * 2 * (XWO / 2)) {
        const int run = tid % 7;
        const int r   = tid / 7;
        const int g4b = r & 1;
        const int y   = r >> 1;
        const int xb  = run * 2;
        float4 rv[8];
        #pragma unroll
        for (int j = 0; j < 8; ++j)
            rv[j] = vs[vsIdx(g4b, y, xb + j)];
        float4 s0 = rv[0];
        #pragma unroll
        for (int j = 1; j < 7; ++j) s0 = f4add(s0, rv[j]);
        float4 s1 = f4add(s0, f4sub(rv[7], rv[0]));
        const float inv = 1.f / 49.f;
        float* ob = out + ((size_t)(b * CINn + g * 8 + g4b * 4) * Hn + y) * Wn
                        + x0out + xb;
        float2 st;
        st.x = s0.x * inv; st.y = s1.x * inv; *(float2*)(ob + 0 * PLANE) = st;
        st.x = s0.y * inv; st.y = s1.y * inv; *(float2*)(ob + 1 * PLANE) = st;
        st.x = s0.z * inv; st.y = s1.z * inv; *(float2*)(ob + 2 * PLANE) = st;
        st.x = s0.w * inv; st.y = s1.w * inv; *(float2*)(ob + 3 * PLANE) = st;
    }
}

extern "C" void kernel_launch(void* const* d_in, const int* in_sizes, int n_in,
                              void* d_out, int out_size, void* d_ws, size_t ws_size,
                              hipStream_t stream) {
    // setup_inputs order: x, wq, wk, wv, rel_h, rel_w
    const float* x  = (const float*)d_in[0];
    const float* wv = (const float*)d_in[3];
    float* out = (float*)d_out;

    dim3 grid(Bn * HEADSn * NSTRIP);   // 256 blocks = 1 per CU
    saconv_r5<<<grid, THREADS, 0, stream>>>(x, wv, out);
}

// Round 7
// 10.801 us; speedup vs baseline: 1.3083x; 1.1647x over previous
//
#include <hip/hip_runtime.h>

// SAConv: reference's scale = sqrt(heads // COUT) = 0 (Python int division)
// => softmax uniform => out = 7x7 box-mean of v = hswish(grouped_1x1(pad(x), wv)).
// q/k/rel_* are dead code.
//
// R6 = R2 skeleton (256-thread blocks, conv->LDS, vertical sliding sum,
// horizontal sliding sum) with TH=8 rows/tile:
//  - conv positions 555k -> 389k (halo 14/8 = 1.75x vs R2's 10/4 = 2.5x);
//    R3/R4 measured ~1.55us per 334k positions => ~-0.7us.
//  - P2 sliding window 10 reads -> 4 output rows (2.5 reads/out vs R2's 4).
//  - sx() swizzle dropped: every LDS phase reads with lane-contiguous
//    columns (conflict-free by construction); RS=63 (1-pad).
//  - LDS 44.6KB -> 3 blocks/CU, 448 blocks (all co-resident, 12 waves/CU).

namespace {
constexpr int Bn = 8, CINn = 64, Hn = 56, Wn = 56;
constexpr int HEADSn = 8;
constexpr int PADn = 3;
constexpr int TH = 8;                  // output rows per block
constexpr int NTILES = Hn / TH;        // 7
constexpr int PH = TH + 6;             // 14 staged conv rows
constexpr int PW = Wn + 6;             // 62 staged cols
constexpr int RS = PW + 1;             // 63: row stride in float4
constexpr int THREADS = 256;
constexpr int NRUNS = Wn / 2;          // 28
constexpr int PLANE = Hn * Wn;         // 3136
}

__device__ __forceinline__ float4 f4add(float4 a, float4 b) {
    return make_float4(a.x + b.x, a.y + b.y, a.z + b.z, a.w + b.w);
}
__device__ __forceinline__ float4 f4sub(float4 a, float4 b) {
    return make_float4(a.x - b.x, a.y - b.y, a.z - b.z, a.w - b.w);
}

__global__ __launch_bounds__(THREADS) void saconv_r6(
    const float* __restrict__ x, const float* __restrict__ wv,
    float* __restrict__ out)
{
    __shared__ float  wvs[64];             // this head's wv[o][i]
    __shared__ float4 vt[2 * PH * RS];     // 28.2 KB, [g4][convrow][col]
    __shared__ float4 vs[2 * TH * RS];     // 16.1 KB, [g4][outrow][col]

    const int bid  = blockIdx.x;
    const int tile = bid % NTILES;
    const int g    = (bid / NTILES) % HEADSn;
    const int b    = bid / (NTILES * HEADSn);
    const int h0   = tile * TH;
    const int tid  = threadIdx.x;

    if (tid < 64) wvs[tid] = wv[g * 64 + tid];
    __syncthreads();

    const float* __restrict__ xg = x + (size_t)(b * CINn + g * 8) * PLANE;

    // ---- P1: conv(8->8) + hswish over 14x62 padded tile ----
    for (int p = tid; p < PH * PW; p += THREADS) {
        const int py = p / PW;
        const int px = p - py * PW;
        const int y  = h0 + py - PADn;
        const int xx = px - PADn;
        float4 v0 = make_float4(0.f, 0.f, 0.f, 0.f);
        float4 v1 = v0;
        if ((unsigned)y < (unsigned)Hn && (unsigned)xx < (unsigned)Wn) {
            float in[8];
            #pragma unroll
            for (int i = 0; i < 8; ++i)
                in[i] = xg[i * PLANE + y * Wn + xx];
            float a[8];
            #pragma unroll
            for (int o = 0; o < 8; ++o) {
                float s = 0.f;
                #pragma unroll
                for (int i = 0; i < 8; ++i)
                    s = fmaf(wvs[o * 8 + i], in[i], s);
                float t = fminf(fmaxf(s + 3.f, 0.f), 6.f);
                a[o] = s * t * (1.f / 6.f);
            }
            v0 = make_float4(a[0], a[1], a[2], a[3]);
            v1 = make_float4(a[4], a[5], a[6], a[7]);
        }
        vt[(0 * PH + py) * RS + px] = v0;
        vt[(1 * PH + py) * RS + px] = v1;
    }
    __syncthreads();

    // ---- P2: vertical sliding 7-sum (10 reads -> 4 output rows) ----
    // item = (rowgrp 0..1, x 0..61, g4): 248 threads
    if (tid < 2 * PW * 2) {
        const int g4     = tid & 1;
        const int r      = tid >> 1;          // 0..123
        const int xx     = r % PW;
        const int rowgrp = r / PW;            // 0 or 1
        const int r0     = rowgrp * 4;        // output rows r0..r0+3
        float4 win[10];
        #pragma unroll
        for (int j = 0; j < 10; ++j)
            win[j] = vt[(g4 * PH + r0 + j) * RS + xx];
        float4 s = win[0];
        #pragma unroll
        for (int j = 1; j < 7; ++j) s = f4add(s, win[j]);
        vs[(g4 * TH + r0) * RS + xx] = s;
        #pragma unroll
        for (int k = 1; k < 4; ++k) {
            s = f4add(s, f4sub(win[k + 6], win[k - 1]));
            vs[(g4 * TH + r0 + k) * RS + xx] = s;
        }
    }
    __syncthreads();

    // ---- P3: horizontal sliding 7-sum (run of 2) + scale + store ----
    // item = (y 0..7, run 0..27, g4): 448 items, 2 passes of 224
    #pragma unroll
    for (int it = tid; it < TH * NRUNS * 2; it += THREADS) {
        const int g4  = it & 1;
        const int r   = it >> 1;              // 0..223
        const int run = r % NRUNS;
        const int y   = r / NRUNS;            // 0..7
        const int x0  = run * 2;
        float4 rv[8];
        #pragma unroll
        for (int j = 0; j < 8; ++j)
            rv[j] = vs[(g4 * TH + y) * RS + x0 + j];
        float4 s0 = rv[0];
        #pragma unroll
        for (int j = 1; j < 7; ++j) s0 = f4add(s0, rv[j]);
        float4 s1 = f4add(s0, f4sub(rv[7], rv[0]));
        const float inv = 1.f / 49.f;
        float* ob = out + ((size_t)(b * CINn + g * 8 + g4 * 4) * Hn + (h0 + y)) * Wn + x0;
        float2 st;
        st.x = s0.x * inv; st.y = s1.x * inv; *(float2*)(ob + 0 * PLANE) = st;
        st.x = s0.y * inv; st.y = s1.y * inv; *(float2*)(ob + 1 * PLANE) = st;
        st.x = s0.z * inv; st.y = s1.z * inv; *(float2*)(ob + 2 * PLANE) = st;
        st.x = s0.w * inv; st.y = s1.w * inv; *(float2*)(ob + 3 * PLANE) = st;
    }
}

extern "C" void kernel_launch(void* const* d_in, const int* in_sizes, int n_in,
                              void* d_out, int out_size, void* d_ws, size_t ws_size,
                              hipStream_t stream) {
    // setup_inputs order: x, wq, wk, wv, rel_h, rel_w
    const float* x  = (const float*)d_in[0];
    const float* wv = (const float*)d_in[3];
    float* out = (float*)d_out;

    dim3 grid(Bn * HEADSn * NTILES);   // 448 blocks
    saconv_r6<<<grid, THREADS, 0, stream>>>(x, wv, out);
}